// Round 11
// baseline (164.776 us; speedup 1.0000x reference)
//
#include <hip/hip_runtime.h>

// ActivatedAttention: out = transpose(GroupNorm( relu(rope(Q)) @ [relu(rope(K))^T @ relu(V)] )).
// B=4, T=2048, D=1024. y = Q @ (K^T V)  (no softmax -> associativity).
// All GEMMs hi-only bf16 (absmax 0.0234 vs threshold 0.0728, bench-validated).
// Core: 128x128 tile, 4 waves of 64x64 via 4x4 mfma_16x16x32, BK=32 with PACKED LDS
// layout (128x32 tile stored as 64 super-rows x 64 cols; row pair per 128B row, 8-slot
// XOR swizzle slot^=sr&7 -> 2 lanes/bank = free). Double-buffered global_load_lds,
// counted vmcnt(4). LDS: gemm1f 33.3KB -> 4 blocks/CU, gemm2/3 32KB -> 5 blocks/CU
// (occupancy is the lever: r10 was 2 blocks/CU, latency-bound at MfmaUtil 30%).
// Barrier skeleton (r7-proven): vmcnt(N); s_barrier; sched_barrier; ds_reads;
// lgkmcnt(0); sched_barrier; s_barrier; MFMAs (overlap next staging).
// gemm1 fuses table-rope/relu/bf16 epilogue via f32 LDS tile [n][m-half] x2;
// gemm3 fuses GroupNorm + transposed store.

typedef unsigned short u16;
typedef __attribute__((ext_vector_type(8))) unsigned short u16x8;
typedef __attribute__((ext_vector_type(4))) float fx4;
typedef __attribute__((ext_vector_type(8))) __bf16 bfx8;

#define TP 65  // epilogue f32 half-tile pitch (128 rows x 64+1)

__device__ __forceinline__ u16 f2bh(float v) {  // f32 -> bf16 RNE
  unsigned u = __float_as_uint(v);
  return (u16)((u + 0x7FFFu + ((u >> 16) & 1u)) >> 16);
}
__device__ __forceinline__ fx4 mfma16(bfx8 a, bfx8 b, fx4 c) {
  return __builtin_amdgcn_mfma_f32_16x16x32_bf16(a, b, c, 0, 0, 0);
}

__device__ __forceinline__ void gload16(const u16* g, u16* l) {
  __builtin_amdgcn_global_load_lds(
      (const __attribute__((address_space(1))) unsigned int*)(const void*)g,
      (__attribute__((address_space(3))) unsigned int*)(void*)l, 16, 0, 0);
}

// Packed swizzled LDS read: tile row 'row' (0..127), k-slot lk (0..3, 8 bf16 each).
// super-row sr=row>>1 (128B), logical slot t=(row&1)*4+lk, physical t^(sr&7).
__device__ __forceinline__ bfx8 ldsw32(const u16* lds, int row, int lk) {
  int sr = row >> 1;
  int t = ((row & 1) << 2) + lk;
  const char* p = (const char*)lds + sr * 128 + ((t ^ (sr & 7)) << 4);
  return __builtin_bit_cast(bfx8, *reinterpret_cast<const u16x8*>(p));
}

// Stage 128 rows x 32 cols (packed, 2 chunks/thread). Linear LDS dest, pre-swizzled
// global source so the read-side XOR matches (both-sides-or-neither).
__device__ __forceinline__ void stage2(const u16* __restrict__ A,
                                       size_t rowBase, int stride, int k0,
                                       u16* lds, int w, int lane) {
#pragma unroll
  for (int i = 0; i < 2; ++i) {
    int c = ((w * 2 + i) << 6) + lane;  // chunk 0..511
    int sr = c >> 3, s = c & 7;
    int t = s ^ (sr & 7);
    int row = 2 * sr + (t >> 2);
    const u16* src = A + (rowBase + (size_t)row) * (size_t)stride + k0 + ((t & 3) << 3);
    gload16(src, lds + ((w * 2 + i) << 9));
  }
}

// ---- Pipelined hi-only 128x128 GEMM core, BK=32 packed, dbuf staging.
// Per wave per K-step: 4 gload (next) -> vmcnt(4) -> barrier -> 8 ds_read_b128 ->
// lgkmcnt(0) -> barrier -> 16 MFMA (overlap next staging).
__device__ inline void gemm_core_pipe(const u16* __restrict__ A, size_t aBase, int aStr,
                                      const u16* __restrict__ B, size_t bBase, int bStr, int K,
                                      u16* sA0, u16* sB0, u16* sA1, u16* sB1,
                                      fx4 acc[4][4], int w, int lane) {
  int wm = (w >> 1) * 64, wn = (w & 1) * 64;
  int lr = lane & 15, lk = lane >> 4;
  stage2(A, aBase, aStr, 0, sA0, w, lane);
  stage2(B, bBase, bStr, 0, sB0, w, lane);
  int NT = K >> 5;
  for (int t = 0; t < NT; ++t) {
    u16* cA = (t & 1) ? sA1 : sA0;
    u16* cB = (t & 1) ? sB1 : sB0;
    if (t + 1 < NT) {
      u16* nA = (t & 1) ? sA0 : sA1;
      u16* nB = (t & 1) ? sB0 : sB1;
      stage2(A, aBase, aStr, (t + 1) << 5, nA, w, lane);
      stage2(B, bBase, bStr, (t + 1) << 5, nB, w, lane);
      asm volatile("s_waitcnt vmcnt(4)" ::: "memory");  // tile-t loads done, 4 in flight
    } else {
      asm volatile("s_waitcnt vmcnt(0)" ::: "memory");
    }
    __builtin_amdgcn_s_barrier();       // tile t resident (all waves)
    __builtin_amdgcn_sched_barrier(0);  // do NOT hoist reads above the barrier (race!)
    bfx8 a[4], b[4];
#pragma unroll
    for (int i = 0; i < 4; ++i) {
      a[i] = ldsw32(cA, wm + i * 16 + lr, lk);
      b[i] = ldsw32(cB, wn + i * 16 + lr, lk);
    }
    asm volatile("s_waitcnt lgkmcnt(0)" ::: "memory");  // reads landed in regs
    __builtin_amdgcn_sched_barrier(0);
    __builtin_amdgcn_s_barrier();       // WAR: buffers free; MFMAs overlap next staging
#pragma unroll
    for (int mi = 0; mi < 4; ++mi)
#pragma unroll
      for (int ni = 0; ni < 4; ++ni)
        acc[mi][ni] = mfma16(a[mi], b[ni], acc[mi][ni]);
  }
}

// ---- K0: merged prep: castX (blocks 0..4095), transW (4096..7167), ropetab (7168..15359)
__global__ void k_prep(const float* __restrict__ x, const float* __restrict__ W,
                       u16* __restrict__ xh, u16* __restrict__ WTh,
                       float2* __restrict__ tabTI, float2* __restrict__ tabIT) {
  __shared__ float tile[32][33];
  int bid = blockIdx.x, tid = threadIdx.x;
  if (bid < 4096) {  // cast x -> bf16, 8 elems/thread
    size_t i = ((size_t)bid * 256 + tid) * 8;
    fx4 v0 = *reinterpret_cast<const fx4*>(x + i);
    fx4 v1 = *reinterpret_cast<const fx4*>(x + i + 4);
    u16x8 h;
#pragma unroll
    for (int j = 0; j < 4; ++j) {
      h[j] = f2bh(v0[j]);
      h[4 + j] = f2bh(v1[j]);
    }
    *reinterpret_cast<u16x8*>(xh + i) = h;
  } else if (bid < 7168) {  // transpose W -> WT[3072][1024] bf16
    int idx = bid - 4096;
    int n0 = (idx % 96) * 32, k0 = (idx / 96) * 32;
    int c = tid & 31, r4 = tid >> 5;
#pragma unroll
    for (int it = 0; it < 4; ++it) {
      int r = r4 + it * 8;
      tile[r][c] = W[(size_t)(k0 + r) * 3072 + n0 + c];
    }
    __syncthreads();
#pragma unroll
    for (int it = 0; it < 4; ++it) {
      int r = r4 + it * 8;
      WTh[(size_t)(n0 + r) * 1024 + k0 + c] = f2bh(tile[c][r]);
    }
  } else {  // rope tables: float2(cos,sin)
    int half = (bid - 7168) >> 12;  // 0: tabTI, 1: tabIT
    int idx = ((bid - 7168) & 4095) * 256 + tid;
    int t, i;
    if (half == 0) {
      t = idx >> 9;
      i = idx & 511;
    } else {
      i = idx >> 11;
      t = idx & 2047;
    }
    float invf = exp2f(-(float)i * (13.287712379549449f / 512.f));  // 10000^(-i/512)
    float ang = (float)t * invf, s, c;
    sincosf(ang, &s, &c);
    if (half == 0)
      tabTI[idx] = make_float2(c, s);
    else
      tabIT[idx] = make_float2(c, s);
  }
}

// ---- G1 fused: relu(rope(x@W+b)) -> Qh row-major, Kth/Vth transposed [B][D][T]
__global__ __launch_bounds__(256) void k_gemm1f(const u16* __restrict__ xh,
                                                const u16* __restrict__ WTh,
                                                const float* __restrict__ b_in,
                                                const float2* __restrict__ tabTI,
                                                const float2* __restrict__ tabIT,
                                                u16* __restrict__ Qh, u16* __restrict__ Kth,
                                                u16* __restrict__ Vth) {
  __shared__ __align__(16) float shbuf[128 * TP];  // 33.3KB; 4x8KB staging aliases it
  u16* sA0 = (u16*)shbuf;
  u16* sB0 = sA0 + 64 * 64;
  u16* sA1 = sB0 + 64 * 64;
  u16* sB1 = sA1 + 64 * 64;
  // XCD-chunked swizzle: 1536 blocks = 8 XCD x (8 mt x 24 nt), mt-fastest within chunk.
  int bid = blockIdx.x;
  int xcd = bid & 7, idx = bid >> 3;
  int mt = (xcd << 3) + (idx & 7), nt = idx >> 3;
  int m0 = mt << 7, n0 = nt << 7;
  int tid = threadIdx.x, lane = tid & 63, w = tid >> 6;
  int wm = (w >> 1) * 64, wn = (w & 1) * 64;
  int lr = lane & 15, lk = lane >> 4;
  fx4 acc[4][4];
#pragma unroll
  for (int i = 0; i < 4; ++i)
#pragma unroll
    for (int j = 0; j < 4; ++j) acc[i][j] = fx4{0.f, 0.f, 0.f, 0.f};

  gemm_core_pipe(xh, (size_t)m0, 1024, WTh, (size_t)n0, 1024, 1024,
                 sA0, sB0, sA1, sB1, acc, w, lane);

  // ---- Epilogue in 2 m-halves of 64 cols through the f32 tile [n 128][m-half 64].
  int part = n0 >> 10;  // 0=Q, 1=K, 2=V (uniform per block)
  int d0 = n0 - (part << 10);
  int bb = m0 >> 11, tbase = m0 & 2047;  // tiles never cross batch boundary
  float bv[4];
#pragma unroll
  for (int ni = 0; ni < 4; ++ni) bv[ni] = b_in[n0 + wn + ni * 16 + lr];

#pragma unroll
  for (int h = 0; h < 2; ++h) {
    __syncthreads();  // staging/core reads or previous half's reads complete
    if ((w >> 1) == h) {
      // this wave's m-range lies in half h: write acc+bias as [n_local][m_half]
#pragma unroll
      for (int mi = 0; mi < 4; ++mi)
#pragma unroll
        for (int ni = 0; ni < 4; ++ni)
#pragma unroll
          for (int r = 0; r < 4; ++r) {
            int ml = mi * 16 + lk * 4 + r;  // 0..63 within half
            int nl = wn + ni * 16 + lr;
            shbuf[nl * TP + ml] = acc[mi][ni][r] + bv[ni];
          }
    }
    __syncthreads();
    int tb = tbase + h * 64;
    if (part == 2) {  // V: relu, store [d][t] (64 t per half)
#pragma unroll
      for (int pass = 0; pass < 4; ++pass) {
        int item = pass * 256 + tid;
        int nl = item >> 3, c8 = (item & 7) * 8;
        u16x8 o;
#pragma unroll
        for (int j = 0; j < 8; ++j) o[j] = f2bh(fmaxf(shbuf[nl * TP + c8 + j], 0.f));
        *reinterpret_cast<u16x8*>(Vth + (((size_t)(bb << 10) + d0 + nl) << 11) + tb + c8) = o;
      }
    } else if (part == 1) {  // K: rope rows (d, d^1) + relu, store [d][t]
#pragma unroll
      for (int pass = 0; pass < 4; ++pass) {
        int item = pass * 256 + tid;
        int nl = item >> 3, c8 = (item & 7) * 8;
        int d = d0 + nl;
        const float2* tp = tabIT + ((size_t)(d >> 1) << 11) + tb + c8;
        const float* e = shbuf + (nl & ~1) * TP + c8;
        const float* oo = shbuf + (nl | 1) * TP + c8;
        int isOdd = d & 1;
        u16x8 o;
#pragma unroll
        for (int j = 0; j < 8; ++j) {
          float2 cs = tp[j];
          float x1 = e[j], x2 = oo[j];
          float v = isOdd ? (x1 * cs.y + x2 * cs.x) : (x1 * cs.x - x2 * cs.y);
          o[j] = f2bh(fmaxf(v, 0.f));
        }
        *reinterpret_cast<u16x8*>(Kth + (((size_t)(bb << 10) + d) << 11) + tb + c8) = o;
      }
    } else {  // Q: rope along d, store [m][d] (64 m per half, 128 d)
#pragma unroll
      for (int pass = 0; pass < 4; ++pass) {
        int item = pass * 256 + tid;
        int ml = item >> 4, c16 = (item & 15) * 8;
        int m = m0 + h * 64 + ml, t = m & 2047;
        const float2* tp = tabTI + ((size_t)t << 9) + ((d0 + c16) >> 1);
        u16x8 o;
#pragma unroll
        for (int jp = 0; jp < 4; ++jp) {
          float x1 = shbuf[(c16 + 2 * jp) * TP + ml];
          float x2 = shbuf[(c16 + 2 * jp + 1) * TP + ml];
          float2 cs = tp[jp];
          o[2 * jp] = f2bh(fmaxf(x1 * cs.x - x2 * cs.y, 0.f));
          o[2 * jp + 1] = f2bh(fmaxf(x1 * cs.y + x2 * cs.x, 0.f));
        }
        *reinterpret_cast<u16x8*>(Qh + ((size_t)m << 10) + d0 + c16) = o;
      }
    }
  }
}

// ---- G2: KtVT[b][n][m] = (K^T V)[m][n], bf16 out. 256 blocks, 2 XCDs per batch.
__global__ __launch_bounds__(256) void k_gemm2(const u16* __restrict__ Kth, const u16* __restrict__ Vth,
                                               u16* __restrict__ KtVTh) {
  __shared__ u16 smem[4 * 64 * 64];  // 32KB -> 5 blocks/CU
  u16* sA0 = smem;
  u16* sB0 = sA0 + 64 * 64;
  u16* sA1 = sB0 + 64 * 64;
  u16* sB1 = sA1 + 64 * 64;
  fx4 acc[4][4];
#pragma unroll
  for (int i = 0; i < 4; ++i)
#pragma unroll
    for (int j = 0; j < 4; ++j) acc[i][j] = fx4{0.f, 0.f, 0.f, 0.f};
  // XCD swizzle: xcd owns (b = xcd>>1, 4 mt x 8 nt), mt-fastest -> A slice 2MB resident.
  int bid = blockIdx.x;
  int xcd = bid & 7, idx = bid >> 3;
  int b = xcd >> 1;
  int mt = (xcd & 1) * 4 + (idx & 3), nt = idx >> 2;
  int m0 = mt << 7, n0 = nt << 7;
  int tid = threadIdx.x, lane = tid & 63, w = tid >> 6;
  const u16* Ab = Kth + ((size_t)b << 21);
  const u16* Bb = Vth + ((size_t)b << 21);
  gemm_core_pipe(Ab, (size_t)m0, 2048, Bb, (size_t)n0, 2048, 2048,
                 sA0, sB0, sA1, sB1, acc, w, lane);
  int wm = (w >> 1) * 64, wn = (w & 1) * 64, lr = lane & 15, lk = lane >> 4;
#pragma unroll
  for (int mi = 0; mi < 4; ++mi)
#pragma unroll
    for (int ni = 0; ni < 4; ++ni)
#pragma unroll
      for (int r = 0; r < 4; ++r) {
        int m = m0 + wm + mi * 16 + lk * 4 + r;
        int n = n0 + wn + ni * 16 + lr;
        KtVTh[((size_t)b << 20) + ((size_t)n << 10) + m] = f2bh(acc[mi][ni][r]);
      }
}

// ---- G3 fused: y = Q @ KtV, then GroupNorm(32-ch groups) + transposed store out[b][d][t].
// 512 blocks, 2 XCDs per batch.
__global__ __launch_bounds__(256) void k_gemm3g(const u16* __restrict__ Qh, const u16* __restrict__ KtVTh,
                                                const float* __restrict__ gw, const float* __restrict__ gb,
                                                float* __restrict__ out) {
  __shared__ u16 smem[4 * 64 * 64];
  u16* sA0 = smem;
  u16* sB0 = sA0 + 64 * 64;
  u16* sA1 = sB0 + 64 * 64;
  u16* sB1 = sA1 + 64 * 64;
  fx4 acc[4][4];
#pragma unroll
  for (int i = 0; i < 4; ++i)
#pragma unroll
    for (int j = 0; j < 4; ++j) acc[i][j] = fx4{0.f, 0.f, 0.f, 0.f};
  int bid = blockIdx.x;
  int xcd = bid & 7, idx = bid >> 3;  // idx 0..63
  int b = xcd >> 1;
  int mt = (xcd & 1) * 8 + (idx & 7), nt = idx >> 3;
  int m0 = mt << 7, n0 = nt << 7;
  int tid = threadIdx.x, lane = tid & 63, w = tid >> 6;
  gemm_core_pipe(Qh, (size_t)(b * 2048 + m0), 1024, KtVTh + ((size_t)b << 20), (size_t)n0, 1024,
                 1024, sA0, sB0, sA1, sB1, acc, w, lane);
  int wm = (w >> 1) * 64, wn = (w & 1) * 64, lr = lane & 15, lk = lane >> 4;
  float wv[4], bvv[4];
#pragma unroll
  for (int ni = 0; ni < 4; ++ni) {
    int n = n0 + wn + ni * 16 + lr;
    wv[ni] = gw[n];
    bvv[ni] = gb[n];
  }
#pragma unroll
  for (int mi = 0; mi < 4; ++mi) {
    fx4 o0, o1, o2, o3;
#pragma unroll
    for (int r = 0; r < 4; ++r) {
      float v0 = acc[mi][0][r], v1 = acc[mi][1][r], v2 = acc[mi][2][r], v3 = acc[mi][3][r];
      float sA2 = v0 + v1, sB2 = v2 + v3;
#pragma unroll
      for (int mk = 1; mk <= 8; mk <<= 1) {
        sA2 += __shfl_xor(sA2, mk);
        sB2 += __shfl_xor(sB2, mk);
      }
      float mA = sA2 * (1.f / 32.f), mB = sB2 * (1.f / 32.f);
      float dA = (v0 - mA) * (v0 - mA) + (v1 - mA) * (v1 - mA);
      float dB = (v2 - mB) * (v2 - mB) + (v3 - mB) * (v3 - mB);
#pragma unroll
      for (int mk = 1; mk <= 8; mk <<= 1) {
        dA += __shfl_xor(dA, mk);
        dB += __shfl_xor(dB, mk);
      }
      float rA = rsqrtf(dA * (1.f / 32.f) + 1e-5f);
      float rB = rsqrtf(dB * (1.f / 32.f) + 1e-5f);
      o0[r] = (v0 - mA) * rA * wv[0] + bvv[0];
      o1[r] = (v1 - mA) * rA * wv[1] + bvv[1];
      o2[r] = (v2 - mB) * rB * wv[2] + bvv[2];
      o3[r] = (v3 - mB) * rB * wv[3] + bvv[3];
    }
    int mbase = m0 + wm + mi * 16 + lk * 4;  // t index, 16B-aligned
#pragma unroll
    for (int ni = 0; ni < 4; ++ni) {
      int n = n0 + wn + ni * 16 + lr;
      fx4 ov = (ni == 0) ? o0 : (ni == 1) ? o1 : (ni == 2) ? o2 : o3;
      *reinterpret_cast<fx4*>(out + (((size_t)(b << 10) + n) << 11) + mbase) = ov;
    }
  }
}

extern "C" void kernel_launch(void* const* d_in, const int* in_sizes, int n_in,
                              void* d_out, int out_size, void* d_ws, size_t ws_size,
                              hipStream_t stream) {
  const float* x = (const float*)d_in[0];
  const float* W = (const float*)d_in[1];
  const float* b_in = (const float*)d_in[2];
  const float* gnw = (const float*)d_in[3];
  const float* gnb = (const float*)d_in[4];
  float* out = (float*)d_out;
  char* ws = (char*)d_ws;

  // Workspace (bytes): xh@0(16M) WTh@16M(6M) Qh@22M(16M) Kth@38M(16M) Vth@54M(16M)
  // KtVTh@70M(8M) tabTI@78M(8M) tabIT@86M(8M). Total ~94MB.
  u16* xh = (u16*)(ws + 0);
  u16* WTh = (u16*)(ws + 16777216);
  u16* Qh = (u16*)(ws + 23068672);
  u16* Kth = (u16*)(ws + 39845888);
  u16* Vth = (u16*)(ws + 56623104);
  u16* KtVTh = (u16*)(ws + 73400320);
  float2* tabTI = (float2*)(ws + 81788928);
  float2* tabIT = (float2*)(ws + 90177536);

  k_prep<<<15360, 256, 0, stream>>>(x, W, xh, WTh, tabTI, tabIT);
  k_gemm1f<<<1536, 256, 0, stream>>>(xh, WTh, b_in, tabTI, tabIT, Qh, Kth, Vth);
  k_gemm2<<<256, 256, 0, stream>>>(Kth, Vth, KtVTh);
  k_gemm3g<<<512, 256, 0, stream>>>(Qh, KtVTh, gnw, gnb, out);
}

// Round 12
// 147.900 us; speedup vs baseline: 1.1141x; 1.1141x over previous
//
#include <hip/hip_runtime.h>

// ActivatedAttention: out = transpose(GroupNorm( relu(rope(Q)) @ [relu(rope(K))^T @ relu(V)] )).
// B=4, T=2048, D=1024. y = Q @ (K^T V)  (no softmax -> associativity).
// All GEMMs hi-only bf16 (absmax 0.0234 vs threshold 0.0728, bench-validated).
// Core (r10-proven): 128x128 tile, 4 waves of 64x64 via 4x4 mfma_16x16x32, BK=64,
// double-buffered staging, counted vmcnt (never drained mid-loop). Barrier skeleton:
// vmcnt(N); lgkmcnt(0); s_barrier; sched_barrier; ds_reads; lgkmcnt(0); sched_barrier;
// s_barrier; MFMAs.  (r11 lesson: BK=32 doubles per-sync overhead -> regression; keep BK=64.
// r9 lesson: 32x32 MFMA frags are >=4-way bank-conflicted on 128B rows; keep 16x16.)
// gemm1f: A staged from f32 x IN-KERNEL (reg-stage f32->bf16->ds_write, castX pass
// eliminated). A-loads issued BEFORE B gload_lds each iter so the compiler's reg-wait
// (vmcnt<=4) doesn't drain B's in-flight gloads; explicit wait = vmcnt(12).
// gemm2: 64x128 tile, 512 blocks (was 256 = 1 block/CU latency-exposed).
// Staging swizzle: linear LDS dest, XOR-swizzled global source + swizzled ds_read
// (slot ^= row&7 on [rows][64] bf16 buffers) -> conflict-free.

typedef unsigned short u16;
typedef __attribute__((ext_vector_type(8))) unsigned short u16x8;
typedef __attribute__((ext_vector_type(4))) float fx4;
typedef __attribute__((ext_vector_type(8))) __bf16 bfx8;

#define TP 129  // epilogue f32 tile pitch

__device__ __forceinline__ u16 f2bh(float v) {  // f32 -> bf16 RNE
  unsigned u = __float_as_uint(v);
  return (u16)((u + 0x7FFFu + ((u >> 16) & 1u)) >> 16);
}
__device__ __forceinline__ fx4 mfma16(bfx8 a, bfx8 b, fx4 c) {
  return __builtin_amdgcn_mfma_f32_16x16x32_bf16(a, b, c, 0, 0, 0);
}

__device__ __forceinline__ void gload16(const u16* g, u16* l) {
  __builtin_amdgcn_global_load_lds(
      (const __attribute__((address_space(1))) unsigned int*)(const void*)g,
      (__attribute__((address_space(3))) unsigned int*)(void*)l, 16, 0, 0);
}

// Swizzled LDS read: buffer is [rows][8 slots of 16B]; logical slot q of row r
// lives at physical slot q ^ (r&7).
__device__ __forceinline__ bfx8 ldsw(const u16* lds, int row, int slot) {
  const char* p = (const char*)lds + row * 128 + ((slot ^ (row & 7)) << 4);
  return __builtin_bit_cast(bfx8, *reinterpret_cast<const u16x8*>(p));
}

// Stage 128 rows x 64 cols (4 chunks/thread) via global_load_lds.
__device__ __forceinline__ void stage4(const u16* __restrict__ A,
                                       size_t rowBase, int stride, int k0,
                                       u16* lds, int w, int lane) {
#pragma unroll
  for (int i = 0; i < 4; ++i) {
    int c = ((w * 4 + i) << 6) + lane;
    int r = c >> 3, s = c & 7;
    int t = s ^ (r & 7);
    const u16* src = A + (rowBase + (size_t)r) * (size_t)stride + k0 + (t << 3);
    gload16(src, lds + ((w * 4 + i) << 9));
  }
}

// Stage 64 rows x 64 cols (2 chunks/thread) via global_load_lds.
__device__ __forceinline__ void stageA2(const u16* __restrict__ A,
                                        size_t rowBase, int stride, int k0,
                                        u16* lds, int w, int lane) {
#pragma unroll
  for (int i = 0; i < 2; ++i) {
    int c = ((w * 2 + i) << 6) + lane;  // 0..511
    int r = c >> 3, s = c & 7;
    int t = s ^ (r & 7);
    const u16* src = A + (rowBase + (size_t)r) * (size_t)stride + k0 + (t << 3);
    gload16(src, lds + ((w * 2 + i) << 9));
  }
}

// ---- Pipelined hi-only 128x128 GEMM core, BK=64, dbuf staging (r10-proven).
__device__ inline void gemm_core_pipe(const u16* __restrict__ A, size_t aBase, int aStr,
                                      const u16* __restrict__ B, size_t bBase, int bStr, int K,
                                      u16* sA0, u16* sB0, u16* sA1, u16* sB1,
                                      fx4 acc[4][4], int w, int lane) {
  int wm = (w >> 1) * 64, wn = (w & 1) * 64;
  int lr = lane & 15, lk = lane >> 4;
  stage4(A, aBase, aStr, 0, sA0, w, lane);
  stage4(B, bBase, bStr, 0, sB0, w, lane);
  int NT = K >> 6;
  for (int t = 0; t < NT; ++t) {
    u16* cA = (t & 1) ? sA1 : sA0;
    u16* cB = (t & 1) ? sB1 : sB0;
    if (t + 1 < NT) {
      u16* nA = (t & 1) ? sA0 : sA1;
      u16* nB = (t & 1) ? sB0 : sB1;
      stage4(A, aBase, aStr, (t + 1) << 6, nA, w, lane);
      stage4(B, bBase, bStr, (t + 1) << 6, nB, w, lane);
      asm volatile("s_waitcnt vmcnt(8)" ::: "memory");  // tile-t loads done, 8 in flight
    } else {
      asm volatile("s_waitcnt vmcnt(0)" ::: "memory");
    }
    __builtin_amdgcn_s_barrier();       // tile t resident (all waves)
    __builtin_amdgcn_sched_barrier(0);  // do NOT hoist reads above the barrier (race!)
    bfx8 a[8], b[8];
#pragma unroll
    for (int h = 0; h < 2; ++h)
#pragma unroll
      for (int i = 0; i < 4; ++i) {
        a[h * 4 + i] = ldsw(cA, wm + i * 16 + lr, h * 4 + lk);
        b[h * 4 + i] = ldsw(cB, wn + i * 16 + lr, h * 4 + lk);
      }
    asm volatile("s_waitcnt lgkmcnt(0)" ::: "memory");  // reads landed in regs
    __builtin_amdgcn_sched_barrier(0);
    __builtin_amdgcn_s_barrier();       // WAR: buffers free; MFMAs overlap next staging
#pragma unroll
    for (int h = 0; h < 2; ++h)
#pragma unroll
      for (int mi = 0; mi < 4; ++mi)
#pragma unroll
        for (int ni = 0; ni < 4; ++ni)
          acc[mi][ni] = mfma16(a[h * 4 + mi], b[h * 4 + ni], acc[mi][ni]);
  }
}

// ---- K0: merged prep: transW (blocks 0..3071), ropetab (3072..11263)
__global__ void k_prep(const float* __restrict__ W, u16* __restrict__ WTh,
                       float2* __restrict__ tabTI, float2* __restrict__ tabIT) {
  __shared__ float tile[32][33];
  int bid = blockIdx.x, tid = threadIdx.x;
  if (bid < 3072) {  // transpose W -> WT[3072][1024] bf16
    int idx = bid;
    int n0 = (idx % 96) * 32, k0 = (idx / 96) * 32;
    int c = tid & 31, r4 = tid >> 5;
#pragma unroll
    for (int it = 0; it < 4; ++it) {
      int r = r4 + it * 8;
      tile[r][c] = W[(size_t)(k0 + r) * 3072 + n0 + c];
    }
    __syncthreads();
#pragma unroll
    for (int it = 0; it < 4; ++it) {
      int r = r4 + it * 8;
      WTh[(size_t)(n0 + r) * 1024 + k0 + c] = f2bh(tile[c][r]);
    }
  } else {  // rope tables: float2(cos,sin)
    int half = (bid - 3072) >> 12;  // 0: tabTI, 1: tabIT
    int idx = ((bid - 3072) & 4095) * 256 + tid;
    int t, i;
    if (half == 0) {
      t = idx >> 9;
      i = idx & 511;
    } else {
      i = idx >> 11;
      t = idx & 2047;
    }
    float invf = exp2f(-(float)i * (13.287712379549449f / 512.f));  // 10000^(-i/512)
    float ang = (float)t * invf, s, c;
    sincosf(ang, &s, &c);
    if (half == 0)
      tabTI[idx] = make_float2(c, s);
    else
      tabIT[idx] = make_float2(c, s);
  }
}

// ---- G1 fused: relu(rope(x@W+b)) -> Qh row-major, Kth/Vth transposed [B][D][T].
// A staged in-kernel from f32 x (reg-stage -> cvt -> ds_write).
__global__ __launch_bounds__(256) void k_gemm1f(const float* __restrict__ x32,
                                                const u16* __restrict__ WTh,
                                                const float* __restrict__ b_in,
                                                const float2* __restrict__ tabTI,
                                                const float2* __restrict__ tabIT,
                                                u16* __restrict__ Qh, u16* __restrict__ Kth,
                                                u16* __restrict__ Vth) {
  __shared__ __align__(16) float shbuf[128 * TP];  // 66KB; 4x16KB staging buffers alias it
  u16* sA0 = (u16*)shbuf;
  u16* sB0 = sA0 + 128 * 64;
  u16* sA1 = sB0 + 128 * 64;
  u16* sB1 = sA1 + 128 * 64;
  // XCD-chunked swizzle: 1536 blocks = 8 XCD x (8 mt x 24 nt), mt-fastest within chunk.
  int bid = blockIdx.x;
  int xcd = bid & 7, idx = bid >> 3;
  int mt = (xcd << 3) + (idx & 7), nt = idx >> 3;
  int m0 = mt << 7, n0 = nt << 7;
  int tid = threadIdx.x, lane = tid & 63, w = tid >> 6;
  int wm = (w >> 1) * 64, wn = (w & 1) * 64;
  int lr = lane & 15, lk = lane >> 4;
  fx4 acc[4][4];
#pragma unroll
  for (int i = 0; i < 4; ++i)
#pragma unroll
    for (int j = 0; j < 4; ++j) acc[i][j] = fx4{0.f, 0.f, 0.f, 0.f};

  // per-thread A chunk coordinates (chunk c -> row r, pre-swizzled col slot tt)
  int acr[4], act[4];
#pragma unroll
  for (int i = 0; i < 4; ++i) {
    int c = ((w * 4 + i) << 6) + lane;
    acr[i] = c >> 3;
    act[i] = (c & 7) ^ (acr[i] & 7);
  }
  fx4 av[8];

  // Prologue: A(0) f32 loads FIRST, then B(0) gloads; cvt+write A(0)
#pragma unroll
  for (int i = 0; i < 4; ++i) {
    const float* src = x32 + (size_t)(m0 + acr[i]) * 1024 + (act[i] << 3);
    av[i * 2] = *reinterpret_cast<const fx4*>(src);
    av[i * 2 + 1] = *reinterpret_cast<const fx4*>(src + 4);
  }
  stage4(WTh, (size_t)n0, 1024, 0, sB0, w, lane);
#pragma unroll
  for (int i = 0; i < 4; ++i) {
    int c = ((w * 4 + i) << 6) + lane;
    u16x8 hh;
#pragma unroll
    for (int j = 0; j < 4; ++j) {
      hh[j] = f2bh(av[i * 2][j]);
      hh[4 + j] = f2bh(av[i * 2 + 1][j]);
    }
    *reinterpret_cast<u16x8*>(sA0 + (size_t)c * 8) = hh;  // auto vmcnt<=4: B(0) stays in flight
  }

  const int NT = 16;
  for (int t = 0; t < NT; ++t) {
    u16* cA = (t & 1) ? sA1 : sA0;
    u16* cB = (t & 1) ? sB1 : sB0;
    if (t + 1 < NT) {
      u16* nB = (t & 1) ? sB0 : sB1;
      int k0 = (t + 1) << 6;
#pragma unroll
      for (int i = 0; i < 4; ++i) {  // A(t+1) f32 loads FIRST (so reg-wait keeps B in flight)
        const float* src = x32 + (size_t)(m0 + acr[i]) * 1024 + k0 + (act[i] << 3);
        av[i * 2] = *reinterpret_cast<const fx4*>(src);
        av[i * 2 + 1] = *reinterpret_cast<const fx4*>(src + 4);
      }
      stage4(WTh, (size_t)n0, 1024, k0, nB, w, lane);
      asm volatile("s_waitcnt vmcnt(12)" ::: "memory");  // B(t) landed; A(t+1)8+B(t+1)4 in flight
    } else {
      asm volatile("s_waitcnt vmcnt(0)" ::: "memory");
    }
    asm volatile("s_waitcnt lgkmcnt(0)" ::: "memory");  // my A(t) ds_writes visible
    __builtin_amdgcn_s_barrier();       // tile t resident (all waves)
    __builtin_amdgcn_sched_barrier(0);  // do NOT hoist reads above the barrier (race!)
    bfx8 a[8], b[8];
#pragma unroll
    for (int h = 0; h < 2; ++h)
#pragma unroll
      for (int i = 0; i < 4; ++i) {
        a[h * 4 + i] = ldsw(cA, wm + i * 16 + lr, h * 4 + lk);
        b[h * 4 + i] = ldsw(cB, wn + i * 16 + lr, h * 4 + lk);
      }
    asm volatile("s_waitcnt lgkmcnt(0)" ::: "memory");
    __builtin_amdgcn_sched_barrier(0);
    __builtin_amdgcn_s_barrier();       // WAR: buffers free
#pragma unroll
    for (int h = 0; h < 2; ++h)
#pragma unroll
      for (int mi = 0; mi < 4; ++mi)
#pragma unroll
        for (int ni = 0; ni < 4; ++ni)
          acc[mi][ni] = mfma16(a[h * 4 + mi], b[h * 4 + ni], acc[mi][ni]);
    if (t + 1 < NT) {  // cvt+write A(t+1) after MFMAs (load latency covered by MFMA block)
      u16* nA = (t & 1) ? sA0 : sA1;
#pragma unroll
      for (int i = 0; i < 4; ++i) {
        int c = ((w * 4 + i) << 6) + lane;
        u16x8 hh;
#pragma unroll
        for (int j = 0; j < 4; ++j) {
          hh[j] = f2bh(av[i * 2][j]);
          hh[4 + j] = f2bh(av[i * 2 + 1][j]);
        }
        *reinterpret_cast<u16x8*>(nA + (size_t)c * 8) = hh;
      }
    }
  }

  // ---- Epilogue: acc+bias -> f32 LDS tile [n_local][m_local], then store in output
  // order with vectorized u16x8 stores + table-based rope.
  float bv[4];
#pragma unroll
  for (int ni = 0; ni < 4; ++ni) bv[ni] = b_in[n0 + wn + ni * 16 + lr];
  __syncthreads();  // all LDS reads of staging done before overwrite
#pragma unroll
  for (int mi = 0; mi < 4; ++mi)
#pragma unroll
    for (int ni = 0; ni < 4; ++ni)
#pragma unroll
      for (int r = 0; r < 4; ++r)
        shbuf[(wn + ni * 16 + lr) * TP + wm + mi * 16 + lk * 4 + r] = acc[mi][ni][r] + bv[ni];
  __syncthreads();

  int part = n0 >> 10;       // 0=Q, 1=K, 2=V (uniform per block)
  int d0 = n0 - (part << 10);
  int bb = m0 >> 11, tb = m0 & 2047;  // 128-row tiles never cross batch boundary
  int rl0 = tid >> 4;        // row within tile (per pass: +16)
  int cc = (tid & 15) * 8;   // 8-elem column chunk

  if (part == 2) {           // V: relu only, store [d][t]
#pragma unroll
    for (int pass = 0; pass < 8; ++pass) {
      int rl = rl0 + pass * 16;
      u16x8 o;
#pragma unroll
      for (int j = 0; j < 8; ++j) o[j] = f2bh(fmaxf(shbuf[rl * TP + cc + j], 0.f));
      *reinterpret_cast<u16x8*>(Vth + (((size_t)(bb << 10) + d0 + rl) << 11) + tb + cc) = o;
    }
  } else if (part == 1) {    // K: rope (rows d, d^1) + relu, store [d][t]
#pragma unroll
    for (int pass = 0; pass < 8; ++pass) {
      int rl = rl0 + pass * 16;
      int d = d0 + rl;
      const float2* tp = tabIT + ((size_t)(d >> 1) << 11) + tb + cc;
      const float* e = shbuf + (rl & ~1) * TP + cc;   // even row
      const float* oo = shbuf + (rl | 1) * TP + cc;   // odd row
      int isOdd = d & 1;
      u16x8 o;
#pragma unroll
      for (int j = 0; j < 8; ++j) {
        float2 cs = tp[j];
        float x1 = e[j], x2 = oo[j];
        float v = isOdd ? (x1 * cs.y + x2 * cs.x) : (x1 * cs.x - x2 * cs.y);
        o[j] = f2bh(fmaxf(v, 0.f));
      }
      *reinterpret_cast<u16x8*>(Kth + (((size_t)(bb << 10) + d) << 11) + tb + cc) = o;
    }
  } else {                   // Q: rope along d, store [m][d]
#pragma unroll
    for (int pass = 0; pass < 8; ++pass) {
      int rl = rl0 + pass * 16;  // m_local
      int m = m0 + rl, t = m & 2047;
      const float2* tp = tabTI + ((size_t)t << 9) + ((d0 + cc) >> 1);
      u16x8 o;
#pragma unroll
      for (int jp = 0; jp < 4; ++jp) {
        float x1 = shbuf[(cc + 2 * jp) * TP + rl];
        float x2 = shbuf[(cc + 2 * jp + 1) * TP + rl];
        float2 cs = tp[jp];
        o[2 * jp] = f2bh(fmaxf(x1 * cs.x - x2 * cs.y, 0.f));
        o[2 * jp + 1] = f2bh(fmaxf(x1 * cs.y + x2 * cs.x, 0.f));
      }
      *reinterpret_cast<u16x8*>(Qh + ((size_t)m << 10) + d0 + cc) = o;
    }
  }
}

// ---- G2: KtVT[b][n][m] = (K^T V)[m][n], bf16 out. 64x128 tile, 512 blocks (2/CU).
__global__ __launch_bounds__(256) void k_gemm2(const u16* __restrict__ Kth, const u16* __restrict__ Vth,
                                               u16* __restrict__ KtVTh) {
  __shared__ u16 smem[2 * (64 + 128) * 64];  // 48KB -> 3 blocks/CU capacity
  u16* sA0 = smem;
  u16* sB0 = sA0 + 64 * 64;
  u16* sA1 = sB0 + 128 * 64;
  u16* sB1 = sA1 + 64 * 64;
  fx4 acc[4][2];
#pragma unroll
  for (int i = 0; i < 4; ++i)
#pragma unroll
    for (int j = 0; j < 2; ++j) acc[i][j] = fx4{0.f, 0.f, 0.f, 0.f};
  // XCD swizzle: xcd owns (b = xcd>>1, 8 mt x 8 nt), mt-fastest -> A slice 2MB resident.
  int bid = blockIdx.x;
  int xcd = bid & 7, idx = bid >> 3;  // idx 0..63
  int b = xcd >> 1;
  int mt = (xcd & 1) * 8 + (idx & 7), nt = idx >> 3;
  int m0 = mt << 6, n0 = nt << 7;
  int tid = threadIdx.x, lane = tid & 63, w = tid >> 6;
  int wn2 = w * 32;  // wave owns 32 n-cols; full 64 m-rows
  int lr = lane & 15, lk = lane >> 4;
  const u16* Ab = Kth + ((size_t)b << 21);
  const u16* Bb = Vth + ((size_t)b << 21);

  stageA2(Ab, (size_t)m0, 2048, 0, sA0, w, lane);
  stage4(Bb, (size_t)n0, 2048, 0, sB0, w, lane);
  const int NT = 32;  // K=2048
  for (int t = 0; t < NT; ++t) {
    u16* cA = (t & 1) ? sA1 : sA0;
    u16* cB = (t & 1) ? sB1 : sB0;
    if (t + 1 < NT) {
      u16* nA = (t & 1) ? sA0 : sA1;
      u16* nB = (t & 1) ? sB0 : sB1;
      stageA2(Ab, (size_t)m0, 2048, (t + 1) << 6, nA, w, lane);
      stage4(Bb, (size_t)n0, 2048, (t + 1) << 6, nB, w, lane);
      asm volatile("s_waitcnt vmcnt(6)" ::: "memory");
    } else {
      asm volatile("s_waitcnt vmcnt(0)" ::: "memory");
    }
    __builtin_amdgcn_s_barrier();
    __builtin_amdgcn_sched_barrier(0);
    bfx8 a[8], bfr[4];
#pragma unroll
    for (int h = 0; h < 2; ++h) {
#pragma unroll
      for (int i = 0; i < 4; ++i) a[h * 4 + i] = ldsw(cA, i * 16 + lr, h * 4 + lk);
#pragma unroll
      for (int j = 0; j < 2; ++j) bfr[h * 2 + j] = ldsw(cB, wn2 + j * 16 + lr, h * 4 + lk);
    }
    asm volatile("s_waitcnt lgkmcnt(0)" ::: "memory");
    __builtin_amdgcn_sched_barrier(0);
    __builtin_amdgcn_s_barrier();
#pragma unroll
    for (int h = 0; h < 2; ++h)
#pragma unroll
      for (int mi = 0; mi < 4; ++mi)
#pragma unroll
        for (int ni = 0; ni < 2; ++ni)
          acc[mi][ni] = mfma16(a[h * 4 + mi], bfr[h * 2 + ni], acc[mi][ni]);
  }
#pragma unroll
  for (int mi = 0; mi < 4; ++mi)
#pragma unroll
    for (int ni = 0; ni < 2; ++ni)
#pragma unroll
      for (int r = 0; r < 4; ++r) {
        int m = m0 + mi * 16 + lk * 4 + r;
        int n = n0 + wn2 + ni * 16 + lr;
        KtVTh[((size_t)b << 20) + ((size_t)n << 10) + m] = f2bh(acc[mi][ni][r]);
      }
}

// ---- G3 fused: y = Q @ KtV, then GroupNorm(32-ch groups) + transposed store out[b][d][t].
// 512 blocks, 2 XCDs per batch.
__global__ __launch_bounds__(256) void k_gemm3g(const u16* __restrict__ Qh, const u16* __restrict__ KtVTh,
                                                const float* __restrict__ gw, const float* __restrict__ gb,
                                                float* __restrict__ out) {
  __shared__ u16 smem[4 * 128 * 64];
  u16* sA0 = smem;
  u16* sB0 = sA0 + 128 * 64;
  u16* sA1 = sB0 + 128 * 64;
  u16* sB1 = sA1 + 128 * 64;
  fx4 acc[4][4];
#pragma unroll
  for (int i = 0; i < 4; ++i)
#pragma unroll
    for (int j = 0; j < 4; ++j) acc[i][j] = fx4{0.f, 0.f, 0.f, 0.f};
  int bid = blockIdx.x;
  int xcd = bid & 7, idx = bid >> 3;  // idx 0..63
  int b = xcd >> 1;
  int mt = (xcd & 1) * 8 + (idx & 7), nt = idx >> 3;
  int m0 = mt << 7, n0 = nt << 7;
  int tid = threadIdx.x, lane = tid & 63, w = tid >> 6;
  gemm_core_pipe(Qh, (size_t)(b * 2048 + m0), 1024, KtVTh + ((size_t)b << 20), (size_t)n0, 1024,
                 1024, sA0, sB0, sA1, sB1, acc, w, lane);
  int wm = (w >> 1) * 64, wn = (w & 1) * 64, lr = lane & 15, lk = lane >> 4;
  float wv[4], bvv[4];
#pragma unroll
  for (int ni = 0; ni < 4; ++ni) {
    int n = n0 + wn + ni * 16 + lr;
    wv[ni] = gw[n];
    bvv[ni] = gb[n];
  }
#pragma unroll
  for (int mi = 0; mi < 4; ++mi) {
    fx4 o0, o1, o2, o3;
#pragma unroll
    for (int r = 0; r < 4; ++r) {
      float v0 = acc[mi][0][r], v1 = acc[mi][1][r], v2 = acc[mi][2][r], v3 = acc[mi][3][r];
      float sA2 = v0 + v1, sB2 = v2 + v3;
#pragma unroll
      for (int mk = 1; mk <= 8; mk <<= 1) {
        sA2 += __shfl_xor(sA2, mk);
        sB2 += __shfl_xor(sB2, mk);
      }
      float mA = sA2 * (1.f / 32.f), mB = sB2 * (1.f / 32.f);
      float dA = (v0 - mA) * (v0 - mA) + (v1 - mA) * (v1 - mA);
      float dB = (v2 - mB) * (v2 - mB) + (v3 - mB) * (v3 - mB);
#pragma unroll
      for (int mk = 1; mk <= 8; mk <<= 1) {
        dA += __shfl_xor(dA, mk);
        dB += __shfl_xor(dB, mk);
      }
      float rA = rsqrtf(dA * (1.f / 32.f) + 1e-5f);
      float rB = rsqrtf(dB * (1.f / 32.f) + 1e-5f);
      o0[r] = (v0 - mA) * rA * wv[0] + bvv[0];
      o1[r] = (v1 - mA) * rA * wv[1] + bvv[1];
      o2[r] = (v2 - mB) * rB * wv[2] + bvv[2];
      o3[r] = (v3 - mB) * rB * wv[3] + bvv[3];
    }
    int mbase = m0 + wm + mi * 16 + lk * 4;  // t index, 16B-aligned
#pragma unroll
    for (int ni = 0; ni < 4; ++ni) {
      int n = n0 + wn + ni * 16 + lr;
      fx4 ov = (ni == 0) ? o0 : (ni == 1) ? o1 : (ni == 2) ? o2 : o3;
      *reinterpret_cast<fx4*>(out + (((size_t)(b << 10) + n) << 11) + mbase) = ov;
    }
  }
}

extern "C" void kernel_launch(void* const* d_in, const int* in_sizes, int n_in,
                              void* d_out, int out_size, void* d_ws, size_t ws_size,
                              hipStream_t stream) {
  const float* x = (const float*)d_in[0];
  const float* W = (const float*)d_in[1];
  const float* b_in = (const float*)d_in[2];
  const float* gnw = (const float*)d_in[3];
  const float* gnb = (const float*)d_in[4];
  float* out = (float*)d_out;
  char* ws = (char*)d_ws;

  // Workspace (bytes): WTh@16M(6M) Qh@22M(16M) Kth@38M(16M) Vth@54M(16M)
  // KtVTh@70M(8M) tabTI@78M(8M) tabIT@86M(8M). (xh slot @0 now unused.)
  u16* WTh = (u16*)(ws + 16777216);
  u16* Qh = (u16*)(ws + 23068672);
  u16* Kth = (u16*)(ws + 39845888);
  u16* Vth = (u16*)(ws + 56623104);
  u16* KtVTh = (u16*)(ws + 73400320);
  float2* tabTI = (float2*)(ws + 81788928);
  float2* tabIT = (float2*)(ws + 90177536);

  k_prep<<<11264, 256, 0, stream>>>(W, WTh, tabTI, tabIT);
  k_gemm1f<<<1536, 256, 0, stream>>>(x, WTh, b_in, tabTI, tabIT, Qh, Kth, Vth);
  k_gemm2<<<512, 256, 0, stream>>>(Kth, Vth, KtVTh);
  k_gemm3g<<<512, 256, 0, stream>>>(Qh, KtVTh, gnw, gnb, out);
}

// Round 13
// 132.257 us; speedup vs baseline: 1.2459x; 1.1183x over previous
//
#include <hip/hip_runtime.h>

// ActivatedAttention: out = transpose(GroupNorm( relu(rope(Q)) @ [relu(rope(K))^T @ relu(V)] )).
// B=4, T=2048, D=1024. y = Q @ (K^T V)  (no softmax -> associativity).
// All GEMMs hi-only bf16 (absmax 0.0234 vs threshold 0.0728, bench-validated).
// Consolidation of best-measured pieces:
//  - gemm1f: r10 exact (bf16 xh input staged via global_load_lds; NOT in-kernel f32
//    staging -- r12 lesson: f32 A slice = 4MB/XCD thrashes L2, FETCH +45MB, VALU +15%).
//  - gemm2: r12 64x128 tile, 512 blocks (256-block/1-per-CU was latency-exposed).
//  - gemm3g: r10. prep: merged castX+transW+ropetab.
// Core: 128x128 (gemm2: 64x128) tile, 4 waves, mfma_16x16x32, BK=64, dbuf staging,
// counted vmcnt (never drained mid-loop). Barrier skeleton (r7-proven):
// vmcnt(N); s_barrier; sched_barrier; ds_reads; lgkmcnt(0); sched_barrier; s_barrier; MFMAs.
// r11 lesson: BK=32 doubles per-sync overhead -> keep BK=64. r9 lesson: 32x32 MFMA frags
// are >=4-way bank-conflicted on 128B rows -> keep 16x16.
// Staging swizzle: linear LDS dest, XOR-swizzled global source + swizzled ds_read
// (slot ^= row&7 on [rows][64] bf16 buffers) -> conflict-free.

typedef unsigned short u16;
typedef __attribute__((ext_vector_type(8))) unsigned short u16x8;
typedef __attribute__((ext_vector_type(4))) float fx4;
typedef __attribute__((ext_vector_type(8))) __bf16 bfx8;

#define TP 129  // epilogue f32 tile pitch

__device__ __forceinline__ u16 f2bh(float v) {  // f32 -> bf16 RNE
  unsigned u = __float_as_uint(v);
  return (u16)((u + 0x7FFFu + ((u >> 16) & 1u)) >> 16);
}
__device__ __forceinline__ fx4 mfma16(bfx8 a, bfx8 b, fx4 c) {
  return __builtin_amdgcn_mfma_f32_16x16x32_bf16(a, b, c, 0, 0, 0);
}

__device__ __forceinline__ void gload16(const u16* g, u16* l) {
  __builtin_amdgcn_global_load_lds(
      (const __attribute__((address_space(1))) unsigned int*)(const void*)g,
      (__attribute__((address_space(3))) unsigned int*)(void*)l, 16, 0, 0);
}

// Swizzled LDS read: buffer is [rows][8 slots of 16B]; logical slot q of row r
// lives at physical slot q ^ (r&7).
__device__ __forceinline__ bfx8 ldsw(const u16* lds, int row, int slot) {
  const char* p = (const char*)lds + row * 128 + ((slot ^ (row & 7)) << 4);
  return __builtin_bit_cast(bfx8, *reinterpret_cast<const u16x8*>(p));
}

// Stage 128 rows x 64 cols (4 chunks/thread) via global_load_lds.
__device__ __forceinline__ void stage4(const u16* __restrict__ A,
                                       size_t rowBase, int stride, int k0,
                                       u16* lds, int w, int lane) {
#pragma unroll
  for (int i = 0; i < 4; ++i) {
    int c = ((w * 4 + i) << 6) + lane;
    int r = c >> 3, s = c & 7;
    int t = s ^ (r & 7);
    const u16* src = A + (rowBase + (size_t)r) * (size_t)stride + k0 + (t << 3);
    gload16(src, lds + ((w * 4 + i) << 9));
  }
}

// Stage 64 rows x 64 cols (2 chunks/thread) via global_load_lds.
__device__ __forceinline__ void stageA2(const u16* __restrict__ A,
                                        size_t rowBase, int stride, int k0,
                                        u16* lds, int w, int lane) {
#pragma unroll
  for (int i = 0; i < 2; ++i) {
    int c = ((w * 2 + i) << 6) + lane;  // 0..511
    int r = c >> 3, s = c & 7;
    int t = s ^ (r & 7);
    const u16* src = A + (rowBase + (size_t)r) * (size_t)stride + k0 + (t << 3);
    gload16(src, lds + ((w * 2 + i) << 9));
  }
}

// ---- Pipelined hi-only 128x128 GEMM core, BK=64, dbuf staging (r10-proven).
__device__ inline void gemm_core_pipe(const u16* __restrict__ A, size_t aBase, int aStr,
                                      const u16* __restrict__ B, size_t bBase, int bStr, int K,
                                      u16* sA0, u16* sB0, u16* sA1, u16* sB1,
                                      fx4 acc[4][4], int w, int lane) {
  int wm = (w >> 1) * 64, wn = (w & 1) * 64;
  int lr = lane & 15, lk = lane >> 4;
  stage4(A, aBase, aStr, 0, sA0, w, lane);
  stage4(B, bBase, bStr, 0, sB0, w, lane);
  int NT = K >> 6;
  for (int t = 0; t < NT; ++t) {
    u16* cA = (t & 1) ? sA1 : sA0;
    u16* cB = (t & 1) ? sB1 : sB0;
    if (t + 1 < NT) {
      u16* nA = (t & 1) ? sA0 : sA1;
      u16* nB = (t & 1) ? sB0 : sB1;
      stage4(A, aBase, aStr, (t + 1) << 6, nA, w, lane);
      stage4(B, bBase, bStr, (t + 1) << 6, nB, w, lane);
      asm volatile("s_waitcnt vmcnt(8)" ::: "memory");  // tile-t loads done, 8 in flight
    } else {
      asm volatile("s_waitcnt vmcnt(0)" ::: "memory");
    }
    __builtin_amdgcn_s_barrier();       // tile t resident (all waves)
    __builtin_amdgcn_sched_barrier(0);  // do NOT hoist reads above the barrier (race!)
    bfx8 a[8], b[8];
#pragma unroll
    for (int h = 0; h < 2; ++h)
#pragma unroll
      for (int i = 0; i < 4; ++i) {
        a[h * 4 + i] = ldsw(cA, wm + i * 16 + lr, h * 4 + lk);
        b[h * 4 + i] = ldsw(cB, wn + i * 16 + lr, h * 4 + lk);
      }
    asm volatile("s_waitcnt lgkmcnt(0)" ::: "memory");  // reads landed in regs
    __builtin_amdgcn_sched_barrier(0);
    __builtin_amdgcn_s_barrier();       // WAR: buffers free; MFMAs overlap next staging
#pragma unroll
    for (int h = 0; h < 2; ++h)
#pragma unroll
      for (int mi = 0; mi < 4; ++mi)
#pragma unroll
        for (int ni = 0; ni < 4; ++ni)
          acc[mi][ni] = mfma16(a[h * 4 + mi], b[h * 4 + ni], acc[mi][ni]);
  }
}

// ---- K0: merged prep: castX (blocks 0..4095), transW (4096..7167), ropetab (7168..15359)
__global__ void k_prep(const float* __restrict__ x, const float* __restrict__ W,
                       u16* __restrict__ xh, u16* __restrict__ WTh,
                       float2* __restrict__ tabTI, float2* __restrict__ tabIT) {
  __shared__ float tile[32][33];
  int bid = blockIdx.x, tid = threadIdx.x;
  if (bid < 4096) {  // cast x -> bf16, 8 elems/thread
    size_t i = ((size_t)bid * 256 + tid) * 8;
    fx4 v0 = *reinterpret_cast<const fx4*>(x + i);
    fx4 v1 = *reinterpret_cast<const fx4*>(x + i + 4);
    u16x8 h;
#pragma unroll
    for (int j = 0; j < 4; ++j) {
      h[j] = f2bh(v0[j]);
      h[4 + j] = f2bh(v1[j]);
    }
    *reinterpret_cast<u16x8*>(xh + i) = h;
  } else if (bid < 7168) {  // transpose W -> WT[3072][1024] bf16
    int idx = bid - 4096;
    int n0 = (idx % 96) * 32, k0 = (idx / 96) * 32;
    int c = tid & 31, r4 = tid >> 5;
#pragma unroll
    for (int it = 0; it < 4; ++it) {
      int r = r4 + it * 8;
      tile[r][c] = W[(size_t)(k0 + r) * 3072 + n0 + c];
    }
    __syncthreads();
#pragma unroll
    for (int it = 0; it < 4; ++it) {
      int r = r4 + it * 8;
      WTh[(size_t)(n0 + r) * 1024 + k0 + c] = f2bh(tile[c][r]);
    }
  } else {  // rope tables: float2(cos,sin)
    int half = (bid - 7168) >> 12;  // 0: tabTI, 1: tabIT
    int idx = ((bid - 7168) & 4095) * 256 + tid;
    int t, i;
    if (half == 0) {
      t = idx >> 9;
      i = idx & 511;
    } else {
      i = idx >> 11;
      t = idx & 2047;
    }
    float invf = exp2f(-(float)i * (13.287712379549449f / 512.f));  // 10000^(-i/512)
    float ang = (float)t * invf, s, c;
    sincosf(ang, &s, &c);
    if (half == 0)
      tabTI[idx] = make_float2(c, s);
    else
      tabIT[idx] = make_float2(c, s);
  }
}

// ---- G1 fused: relu(rope(x@W+b)) -> Qh row-major, Kth/Vth transposed [B][D][T]
__global__ __launch_bounds__(256) void k_gemm1f(const u16* __restrict__ xh,
                                                const u16* __restrict__ WTh,
                                                const float* __restrict__ b_in,
                                                const float2* __restrict__ tabTI,
                                                const float2* __restrict__ tabIT,
                                                u16* __restrict__ Qh, u16* __restrict__ Kth,
                                                u16* __restrict__ Vth) {
  __shared__ __align__(16) float shbuf[128 * TP];  // 66KB; 4x16KB staging buffers alias it
  u16* sA0 = (u16*)shbuf;
  u16* sB0 = sA0 + 128 * 64;
  u16* sA1 = sB0 + 128 * 64;
  u16* sB1 = sA1 + 128 * 64;
  // XCD-chunked swizzle: 1536 blocks = 8 XCD x (8 mt x 24 nt), mt-fastest within chunk.
  int bid = blockIdx.x;
  int xcd = bid & 7, idx = bid >> 3;
  int mt = (xcd << 3) + (idx & 7), nt = idx >> 3;
  int m0 = mt << 7, n0 = nt << 7;
  int tid = threadIdx.x, lane = tid & 63, w = tid >> 6;
  int wm = (w >> 1) * 64, wn = (w & 1) * 64;
  int lr = lane & 15, lk = lane >> 4;
  fx4 acc[4][4];
#pragma unroll
  for (int i = 0; i < 4; ++i)
#pragma unroll
    for (int j = 0; j < 4; ++j) acc[i][j] = fx4{0.f, 0.f, 0.f, 0.f};

  gemm_core_pipe(xh, (size_t)m0, 1024, WTh, (size_t)n0, 1024, 1024,
                 sA0, sB0, sA1, sB1, acc, w, lane);

  // ---- Epilogue: acc+bias -> f32 LDS tile [n_local][m_local], then store in output
  // order with vectorized u16x8 stores + table-based rope.
  float bv[4];
#pragma unroll
  for (int ni = 0; ni < 4; ++ni) bv[ni] = b_in[n0 + wn + ni * 16 + lr];
  __syncthreads();  // all LDS reads of staging done before overwrite
#pragma unroll
  for (int mi = 0; mi < 4; ++mi)
#pragma unroll
    for (int ni = 0; ni < 4; ++ni)
#pragma unroll
      for (int r = 0; r < 4; ++r)
        shbuf[(wn + ni * 16 + lr) * TP + wm + mi * 16 + lk * 4 + r] = acc[mi][ni][r] + bv[ni];
  __syncthreads();

  int part = n0 >> 10;       // 0=Q, 1=K, 2=V (uniform per block)
  int d0 = n0 - (part << 10);
  int bb = m0 >> 11, tb = m0 & 2047;  // 128-row tiles never cross batch boundary
  int rl0 = tid >> 4;        // row within tile (per pass: +16)
  int cc = (tid & 15) * 8;   // 8-elem column chunk

  if (part == 2) {           // V: relu only, store [d][t]
#pragma unroll
    for (int pass = 0; pass < 8; ++pass) {
      int rl = rl0 + pass * 16;
      u16x8 o;
#pragma unroll
      for (int j = 0; j < 8; ++j) o[j] = f2bh(fmaxf(shbuf[rl * TP + cc + j], 0.f));
      *reinterpret_cast<u16x8*>(Vth + (((size_t)(bb << 10) + d0 + rl) << 11) + tb + cc) = o;
    }
  } else if (part == 1) {    // K: rope (rows d, d^1) + relu, store [d][t]
#pragma unroll
    for (int pass = 0; pass < 8; ++pass) {
      int rl = rl0 + pass * 16;
      int d = d0 + rl;
      const float2* tp = tabIT + ((size_t)(d >> 1) << 11) + tb + cc;
      const float* e = shbuf + (rl & ~1) * TP + cc;   // even row
      const float* oo = shbuf + (rl | 1) * TP + cc;   // odd row
      int isOdd = d & 1;
      u16x8 o;
#pragma unroll
      for (int j = 0; j < 8; ++j) {
        float2 cs = tp[j];
        float x1 = e[j], x2 = oo[j];
        float v = isOdd ? (x1 * cs.y + x2 * cs.x) : (x1 * cs.x - x2 * cs.y);
        o[j] = f2bh(fmaxf(v, 0.f));
      }
      *reinterpret_cast<u16x8*>(Kth + (((size_t)(bb << 10) + d) << 11) + tb + cc) = o;
    }
  } else {                   // Q: rope along d, store [m][d]
#pragma unroll
    for (int pass = 0; pass < 8; ++pass) {
      int rl = rl0 + pass * 16;  // m_local
      int m = m0 + rl, t = m & 2047;
      const float2* tp = tabTI + ((size_t)t << 9) + ((d0 + cc) >> 1);
      u16x8 o;
#pragma unroll
      for (int jp = 0; jp < 4; ++jp) {
        float x1 = shbuf[(cc + 2 * jp) * TP + rl];
        float x2 = shbuf[(cc + 2 * jp + 1) * TP + rl];
        float2 cs = tp[jp];
        o[2 * jp] = f2bh(fmaxf(x1 * cs.x - x2 * cs.y, 0.f));
        o[2 * jp + 1] = f2bh(fmaxf(x1 * cs.y + x2 * cs.x, 0.f));
      }
      *reinterpret_cast<u16x8*>(Qh + ((size_t)m << 10) + d0 + cc) = o;
    }
  }
}

// ---- G2: KtVT[b][n][m] = (K^T V)[m][n], bf16 out. 64x128 tile, 512 blocks (r12-proven).
__global__ __launch_bounds__(256) void k_gemm2(const u16* __restrict__ Kth, const u16* __restrict__ Vth,
                                               u16* __restrict__ KtVTh) {
  __shared__ u16 smem[2 * (64 + 128) * 64];  // 48KB
  u16* sA0 = smem;
  u16* sB0 = sA0 + 64 * 64;
  u16* sA1 = sB0 + 128 * 64;
  u16* sB1 = sA1 + 64 * 64;
  fx4 acc[4][2];
#pragma unroll
  for (int i = 0; i < 4; ++i)
#pragma unroll
    for (int j = 0; j < 2; ++j) acc[i][j] = fx4{0.f, 0.f, 0.f, 0.f};
  // XCD swizzle: xcd owns (b = xcd>>1, 8 mt x 8 nt), mt-fastest -> A slice 2MB resident.
  int bid = blockIdx.x;
  int xcd = bid & 7, idx = bid >> 3;  // idx 0..63
  int b = xcd >> 1;
  int mt = (xcd & 1) * 8 + (idx & 7), nt = idx >> 3;
  int m0 = mt << 6, n0 = nt << 7;
  int tid = threadIdx.x, lane = tid & 63, w = tid >> 6;
  int wn2 = w * 32;  // wave owns 32 n-cols; full 64 m-rows
  int lr = lane & 15, lk = lane >> 4;
  const u16* Ab = Kth + ((size_t)b << 21);
  const u16* Bb = Vth + ((size_t)b << 21);

  stageA2(Ab, (size_t)m0, 2048, 0, sA0, w, lane);
  stage4(Bb, (size_t)n0, 2048, 0, sB0, w, lane);
  const int NT = 32;  // K=2048
  for (int t = 0; t < NT; ++t) {
    u16* cA = (t & 1) ? sA1 : sA0;
    u16* cB = (t & 1) ? sB1 : sB0;
    if (t + 1 < NT) {
      u16* nA = (t & 1) ? sA0 : sA1;
      u16* nB = (t & 1) ? sB0 : sB1;
      stageA2(Ab, (size_t)m0, 2048, (t + 1) << 6, nA, w, lane);
      stage4(Bb, (size_t)n0, 2048, (t + 1) << 6, nB, w, lane);
      asm volatile("s_waitcnt vmcnt(6)" ::: "memory");
    } else {
      asm volatile("s_waitcnt vmcnt(0)" ::: "memory");
    }
    __builtin_amdgcn_s_barrier();
    __builtin_amdgcn_sched_barrier(0);
    bfx8 a[8], bfr[4];
#pragma unroll
    for (int h = 0; h < 2; ++h) {
#pragma unroll
      for (int i = 0; i < 4; ++i) a[h * 4 + i] = ldsw(cA, i * 16 + lr, h * 4 + lk);
#pragma unroll
      for (int j = 0; j < 2; ++j) bfr[h * 2 + j] = ldsw(cB, wn2 + j * 16 + lr, h * 4 + lk);
    }
    asm volatile("s_waitcnt lgkmcnt(0)" ::: "memory");
    __builtin_amdgcn_sched_barrier(0);
    __builtin_amdgcn_s_barrier();
#pragma unroll
    for (int h = 0; h < 2; ++h)
#pragma unroll
      for (int mi = 0; mi < 4; ++mi)
#pragma unroll
        for (int ni = 0; ni < 2; ++ni)
          acc[mi][ni] = mfma16(a[h * 4 + mi], bfr[h * 2 + ni], acc[mi][ni]);
  }
#pragma unroll
  for (int mi = 0; mi < 4; ++mi)
#pragma unroll
    for (int ni = 0; ni < 2; ++ni)
#pragma unroll
      for (int r = 0; r < 4; ++r) {
        int m = m0 + mi * 16 + lk * 4 + r;
        int n = n0 + wn2 + ni * 16 + lr;
        KtVTh[((size_t)b << 20) + ((size_t)n << 10) + m] = f2bh(acc[mi][ni][r]);
      }
}

// ---- G3 fused: y = Q @ KtV, then GroupNorm(32-ch groups) + transposed store out[b][d][t].
// 512 blocks, 2 XCDs per batch.
__global__ __launch_bounds__(256) void k_gemm3g(const u16* __restrict__ Qh, const u16* __restrict__ KtVTh,
                                                const float* __restrict__ gw, const float* __restrict__ gb,
                                                float* __restrict__ out) {
  __shared__ u16 smem[4 * 128 * 64];
  u16* sA0 = smem;
  u16* sB0 = sA0 + 128 * 64;
  u16* sA1 = sB0 + 128 * 64;
  u16* sB1 = sA1 + 128 * 64;
  fx4 acc[4][4];
#pragma unroll
  for (int i = 0; i < 4; ++i)
#pragma unroll
    for (int j = 0; j < 4; ++j) acc[i][j] = fx4{0.f, 0.f, 0.f, 0.f};
  int bid = blockIdx.x;
  int xcd = bid & 7, idx = bid >> 3;  // idx 0..63
  int b = xcd >> 1;
  int mt = (xcd & 1) * 8 + (idx & 7), nt = idx >> 3;
  int m0 = mt << 7, n0 = nt << 7;
  int tid = threadIdx.x, lane = tid & 63, w = tid >> 6;
  gemm_core_pipe(Qh, (size_t)(b * 2048 + m0), 1024, KtVTh + ((size_t)b << 20), (size_t)n0, 1024,
                 1024, sA0, sB0, sA1, sB1, acc, w, lane);
  int wm = (w >> 1) * 64, wn = (w & 1) * 64, lr = lane & 15, lk = lane >> 4;
  float wv[4], bvv[4];
#pragma unroll
  for (int ni = 0; ni < 4; ++ni) {
    int n = n0 + wn + ni * 16 + lr;
    wv[ni] = gw[n];
    bvv[ni] = gb[n];
  }
#pragma unroll
  for (int mi = 0; mi < 4; ++mi) {
    fx4 o0, o1, o2, o3;
#pragma unroll
    for (int r = 0; r < 4; ++r) {
      float v0 = acc[mi][0][r], v1 = acc[mi][1][r], v2 = acc[mi][2][r], v3 = acc[mi][3][r];
      float sA2 = v0 + v1, sB2 = v2 + v3;
#pragma unroll
      for (int mk = 1; mk <= 8; mk <<= 1) {
        sA2 += __shfl_xor(sA2, mk);
        sB2 += __shfl_xor(sB2, mk);
      }
      float mA = sA2 * (1.f / 32.f), mB = sB2 * (1.f / 32.f);
      float dA = (v0 - mA) * (v0 - mA) + (v1 - mA) * (v1 - mA);
      float dB = (v2 - mB) * (v2 - mB) + (v3 - mB) * (v3 - mB);
#pragma unroll
      for (int mk = 1; mk <= 8; mk <<= 1) {
        dA += __shfl_xor(dA, mk);
        dB += __shfl_xor(dB, mk);
      }
      float rA = rsqrtf(dA * (1.f / 32.f) + 1e-5f);
      float rB = rsqrtf(dB * (1.f / 32.f) + 1e-5f);
      o0[r] = (v0 - mA) * rA * wv[0] + bvv[0];
      o1[r] = (v1 - mA) * rA * wv[1] + bvv[1];
      o2[r] = (v2 - mB) * rB * wv[2] + bvv[2];
      o3[r] = (v3 - mB) * rB * wv[3] + bvv[3];
    }
    int mbase = m0 + wm + mi * 16 + lk * 4;  // t index, 16B-aligned
#pragma unroll
    for (int ni = 0; ni < 4; ++ni) {
      int n = n0 + wn + ni * 16 + lr;
      fx4 ov = (ni == 0) ? o0 : (ni == 1) ? o1 : (ni == 2) ? o2 : o3;
      *reinterpret_cast<fx4*>(out + (((size_t)(b << 10) + n) << 11) + mbase) = ov;
    }
  }
}

extern "C" void kernel_launch(void* const* d_in, const int* in_sizes, int n_in,
                              void* d_out, int out_size, void* d_ws, size_t ws_size,
                              hipStream_t stream) {
  const float* x = (const float*)d_in[0];
  const float* W = (const float*)d_in[1];
  const float* b_in = (const float*)d_in[2];
  const float* gnw = (const float*)d_in[3];
  const float* gnb = (const float*)d_in[4];
  float* out = (float*)d_out;
  char* ws = (char*)d_ws;

  // Workspace (bytes): xh@0(16M) WTh@16M(6M) Qh@22M(16M) Kth@38M(16M) Vth@54M(16M)
  // KtVTh@70M(8M) tabTI@78M(8M) tabIT@86M(8M). Total ~94MB.
  u16* xh = (u16*)(ws + 0);
  u16* WTh = (u16*)(ws + 16777216);
  u16* Qh = (u16*)(ws + 23068672);
  u16* Kth = (u16*)(ws + 39845888);
  u16* Vth = (u16*)(ws + 56623104);
  u16* KtVTh = (u16*)(ws + 73400320);
  float2* tabTI = (float2*)(ws + 81788928);
  float2* tabIT = (float2*)(ws + 90177536);

  k_prep<<<15360, 256, 0, stream>>>(x, W, xh, WTh, tabTI, tabIT);
  k_gemm1f<<<1536, 256, 0, stream>>>(xh, WTh, b_in, tabTI, tabIT, Qh, Kth, Vth);
  k_gemm2<<<512, 256, 0, stream>>>(Kth, Vth, KtVTh);
  k_gemm3g<<<512, 256, 0, stream>>>(Qh, KtVTh, gnw, gnb, out);
}